// Round 2
// baseline (586.402 us; speedup 1.0000x reference)
//
#include <hip/hip_runtime.h>
#include <hip/hip_bf16.h>

// MetaUpscale: out[n,o,oy,ox] = sum_{ch<576} patch[n][oy/2][ox/2][ch] * lw[oy][ox][ch][o]
// patch[n][hy][wx][c*9 + kh*3 + kw] = x[n][c][hy+kh-1][wx+kw-1] (zero pad)
// N=2, C=64, H=W=128, S=2 -> out (2,3,256,256). All tensors FP32 (per reference).

namespace {

constexpr int N_  = 2;
constexpr int C_  = 64;
constexpr int H_  = 128;
constexpr int W_  = 128;
constexpr int CH9 = C_ * 9;   // 576
constexpr int OH  = 256;
constexpr int OW  = 256;

__global__ __launch_bounds__(256)
void metaupscale_kernel(const float* __restrict__ x,
                        const float* __restrict__ lw,
                        float* __restrict__ out) {
    __shared__ float patch[N_ * CH9];   // [n][ch], 4.6 KB

    const int blk = blockIdx.x;         // 0 .. H*W-1, one input pixel per block
    const int hy  = blk / W_;
    const int wx  = blk - hy * W_;
    const int tid = threadIdx.x;

    // ---- Stage the 3x3xC patch for BOTH batch images into LDS ----
    for (int e = tid; e < N_ * CH9; e += 256) {
        const int n  = e / CH9;
        const int ch = e - n * CH9;
        const int c  = ch / 9;
        const int j  = ch - c * 9;
        const int h  = hy + (j / 3) - 1;
        const int w  = wx + (j % 3) - 1;
        float v = 0.0f;
        if ((unsigned)h < (unsigned)H_ && (unsigned)w < (unsigned)W_) {
            v = x[((n * C_ + c) * H_ + h) * W_ + w];
        }
        patch[e] = v;
    }
    __syncthreads();

    // ---- Each of the 4 waves handles one output sub-pixel ----
    const int wave = tid >> 6;          // 0..3
    const int lane = tid & 63;
    const int sy   = wave >> 1;
    const int sx   = wave & 1;
    const int oy   = hy * 2 + sy;
    const int ox   = wx * 2 + sx;

    const float* __restrict__ lwp = lw + (size_t)(oy * OW + ox) * (CH9 * 3);

    float acc[N_][3] = {};

    #pragma unroll
    for (int k = 0; k < 9; ++k) {
        const int ch = k * 64 + lane;   // contiguous across the wave
        const float w0 = lwp[ch * 3 + 0];
        const float w1 = lwp[ch * 3 + 1];
        const float w2 = lwp[ch * 3 + 2];
        const float p0 = patch[ch];
        const float p1 = patch[CH9 + ch];
        acc[0][0] += p0 * w0;  acc[0][1] += p0 * w1;  acc[0][2] += p0 * w2;
        acc[1][0] += p1 * w0;  acc[1][1] += p1 * w1;  acc[1][2] += p1 * w2;
    }

    // ---- Reduce the 6 accumulators across the 64-lane wave ----
    #pragma unroll
    for (int off = 32; off > 0; off >>= 1) {
        #pragma unroll
        for (int n = 0; n < N_; ++n) {
            #pragma unroll
            for (int o = 0; o < 3; ++o) {
                acc[n][o] += __shfl_down(acc[n][o], off, 64);
            }
        }
    }

    if (lane == 0) {
        #pragma unroll
        for (int n = 0; n < N_; ++n) {
            #pragma unroll
            for (int o = 0; o < 3; ++o) {
                out[(((size_t)n * 3 + o) * OH + oy) * OW + ox] = acc[n][o];
            }
        }
    }
}

}  // namespace

extern "C" void kernel_launch(void* const* d_in, const int* in_sizes, int n_in,
                              void* d_out, int out_size, void* d_ws, size_t ws_size,
                              hipStream_t stream) {
    const float* x  = (const float*)d_in[0];
    const float* lw = (const float*)d_in[1];
    // d_in[2] = scale (int32, ==2) — compile-time constant here.
    float* out = (float*)d_out;

    const int grid = H_ * W_;   // 16384 blocks, one per input pixel
    metaupscale_kernel<<<grid, 256, 0, stream>>>(x, lw, out);
}